// Round 9
// baseline (774.692 us; speedup 1.0000x reference)
//
#include <hip/hip_runtime.h>
#include <math.h>

#define N1T 65536
#define N2T 16384
#define BSZ 8
#define N1B 8192   // points per batch in xyz1
#define N2B 2048   // points per batch in xyz2
#define C1 256
#define C2 512
#define K1 768     // C1 + C2
#define HID 256
#define BN_EPS 1e-5f

// Exact single-rounded f32 ops via ISA — immune to -ffast-math / contraction.
__device__ __forceinline__ float mul_rn(float a, float b) {
    float r; asm("v_mul_f32 %0, %1, %2" : "=v"(r) : "v"(a), "v"(b)); return r;
}
__device__ __forceinline__ float add_rn(float a, float b) {
    float r; asm("v_add_f32 %0, %1, %2" : "=v"(r) : "v"(a), "v"(b)); return r;
}
__device__ __forceinline__ float sub_rn(float a, float b) {
    float r; asm("v_sub_f32 %0, %1, %2" : "=v"(r) : "v"(a), "v"(b)); return r;
}
__device__ __forceinline__ float fma_rn(float a, float b, float c) {
    float r; asm("v_fma_f32 %0, %1, %2, %3" : "=v"(r) : "v"(a), "v"(b), "v"(c)); return r;
}

// ---------------------------------------------------------------- KNN-3
// Variant ledger (absmax vs ref=np):
//   direct f32 / f64 (true ordering)                      -> 1.46875   REJECTED
//   (qq+kk)-2dot, nofma qq/kk, fma-asc dot                -> 1.052734  REJECTED
//   (qq+kk)-2dot, nofma qq/kk, nofma dot                  -> 1.052734  REJECTED
//   (qq+kk)-2dot, fma qq/kk,   fma-asc dot                -> 1.052734  REJECTED
//     => per-term rounding is irrelevant (common-mode / sub-gap scale).
// This round: OUTER ASSOCIATION change (the only >=3e-6-scale knob left):
//   d2 = (qq - 2*dot) + kk     i.e. numpy "qq[:,None] - 2*dot + kk[None,:]"
//   qq,kk = (x*x + y*y) + z*z  nofma; dot = fma(z,kz, fma(y,ky, rn(x*kx)))
__global__ __launch_bounds__(256) void knn_kernel(
    const float* __restrict__ xyz1, const float* __restrict__ xyz2,
    int* __restrict__ idx_out, float* __restrict__ w_out)
{
    __shared__ float sx[N2B], sy[N2B], sz[N2B], skk[N2B];
    const int tid = threadIdx.x;
    const int qbase = blockIdx.x * 256;      // 256 blocks x 256 queries
    const int batch = qbase / N1B;           // block never straddles batches
    const float* k2 = xyz2 + (size_t)batch * N2B * 3;
    for (int i = tid; i < N2B * 3; i += 256) {
        float v = k2[i];
        int p = i / 3, c = i - 3 * p;
        if (c == 0) sx[p] = v; else if (c == 1) sy[p] = v; else sz[p] = v;
    }
    __syncthreads();
    for (int p = tid; p < N2B; p += 256) {
        float xx = mul_rn(sx[p], sx[p]);
        float yy = mul_rn(sy[p], sy[p]);
        float zz = mul_rn(sz[p], sz[p]);
        skk[p] = add_rn(add_rn(xx, yy), zz);
    }
    __syncthreads();

    const int q = qbase + tid;
    const float qx = xyz1[q * 3 + 0], qy = xyz1[q * 3 + 1], qz = xyz1[q * 3 + 2];
    const float qq = add_rn(add_rn(mul_rn(qx, qx), mul_rn(qy, qy)), mul_rn(qz, qz));
    float b0 = 1e30f, b1 = 1e30f, b2 = 1e30f;
    int i0 = 0, i1 = 0, i2 = 0;
    for (int j = 0; j < N2B; ++j) {
        float p0 = mul_rn(qx, sx[j]);
        float dt = fma_rn(qz, sz[j], fma_rn(qy, sy[j], p0));
        // (qq - 2dot) + kk   <- association under test
        float d  = add_rn(sub_rn(qq, add_rn(dt, dt)), skk[j]);
        if (d < b2) {
            if (d < b1) {
                b2 = b1; i2 = i1;
                if (d < b0) { b1 = b0; i1 = i0; b0 = d; i0 = j; }
                else        { b1 = d;  i1 = j; }
            } else { b2 = d; i2 = j; }
        }
    }
    // dist = sqrt(max(d2,0)); recip = 1/(dist+1e-8); w = recip/sum(recip)
    float d0s = __fsqrt_rn(fmaxf(b0, 0.0f));
    float d1s = __fsqrt_rn(fmaxf(b1, 0.0f));
    float d2s = __fsqrt_rn(fmaxf(b2, 0.0f));
    float r0 = __fdiv_rn(1.0f, add_rn(d0s, 1e-8f));
    float r1 = __fdiv_rn(1.0f, add_rn(d1s, 1e-8f));
    float r2 = __fdiv_rn(1.0f, add_rn(d2s, 1e-8f));
    float rs = add_rn(add_rn(r0, r1), r2);
    w_out[q * 3 + 0] = __fdiv_rn(r0, rs);
    w_out[q * 3 + 1] = __fdiv_rn(r1, rs);
    w_out[q * 3 + 2] = __fdiv_rn(r2, rs);
    idx_out[q * 3 + 0] = batch * N2B + i0;
    idx_out[q * 3 + 1] = batch * N2B + i1;
    idx_out[q * 3 + 2] = batch * N2B + i2;
}

// ------------------------------------------------- IDW interpolation gather
// sum over 3 neighbors: (p0*w0 + p1*w1) + p2*w2, separate roundings (asm).
__global__ __launch_bounds__(128) void interp_kernel(
    const float* __restrict__ points2, const int* __restrict__ idx,
    const float* __restrict__ w, float* __restrict__ interp)
{
    const int row = blockIdx.x;          // one block per output row
    const int c4 = threadIdx.x;          // float4 column, 128 * 4 = 512
    const int j0 = idx[row * 3 + 0], j1 = idx[row * 3 + 1], j2 = idx[row * 3 + 2];
    const float w0 = w[row * 3 + 0], w1 = w[row * 3 + 1], w2 = w[row * 3 + 2];
    const float4 a = ((const float4*)(points2 + (size_t)j0 * C2))[c4];
    const float4 b = ((const float4*)(points2 + (size_t)j1 * C2))[c4];
    const float4 c = ((const float4*)(points2 + (size_t)j2 * C2))[c4];
    float4 o;
    o.x = add_rn(add_rn(mul_rn(a.x, w0), mul_rn(b.x, w1)), mul_rn(c.x, w2));
    o.y = add_rn(add_rn(mul_rn(a.y, w0), mul_rn(b.y, w1)), mul_rn(c.y, w2));
    o.z = add_rn(add_rn(mul_rn(a.z, w0), mul_rn(b.z, w1)), mul_rn(c.z, w2));
    o.w = add_rn(add_rn(mul_rn(a.w, w0), mul_rn(b.w, w1)), mul_rn(c.w, w2));
    ((float4*)(interp + (size_t)row * C2))[c4] = o;
}

// ------------------------------------------------------------ fp32 GEMMs
#define BM 64
#define BN 64
#define BKT 16
#define PADL 68   // padded LDS leading dim (keeps 16B align, kills conflicts)

// y1 = concat(points1, interp) @ W1 + b1
__global__ __launch_bounds__(256) void gemm1_kernel(
    const float* __restrict__ points1, const float* __restrict__ interp,
    const float* __restrict__ W, const float* __restrict__ bias,
    float* __restrict__ out)
{
    __shared__ __align__(16) float As[BKT][PADL];
    __shared__ __align__(16) float Bs[BKT][PADL];
    const int tid = threadIdx.x;
    const int row0 = blockIdx.y * BM;
    const int col0 = blockIdx.x * BN;
    const int tr = tid / 16, tc = tid % 16;
    const int ar = tid / 4, ak = (tid % 4) * 4;    // A staging: row, k-float4
    const int bk = tid / 16, bc = (tid % 16) * 4;  // B staging: k-row, col-float4
    float acc[4][4] = {};

    for (int kt = 0; kt < K1 / BKT; ++kt) {
        const int k0 = kt * BKT;
        float4 a4;
        if (k0 < C1)
            a4 = *(const float4*)(points1 + (size_t)(row0 + ar) * C1 + (k0 + ak));
        else
            a4 = *(const float4*)(interp + (size_t)(row0 + ar) * C2 + (k0 - C1 + ak));
        float4 b4 = *(const float4*)(W + (size_t)(k0 + bk) * HID + col0 + bc);
        __syncthreads();
        As[ak + 0][ar] = a4.x; As[ak + 1][ar] = a4.y;
        As[ak + 2][ar] = a4.z; As[ak + 3][ar] = a4.w;
        *(float4*)(&Bs[bk][bc]) = b4;
        __syncthreads();
#pragma unroll
        for (int k = 0; k < BKT; ++k) {
            const float4 av4 = *(const float4*)(&As[k][tr * 4]);
            const float4 bv4 = *(const float4*)(&Bs[k][tc * 4]);
            const float av[4] = {av4.x, av4.y, av4.z, av4.w};
            const float bv[4] = {bv4.x, bv4.y, bv4.z, bv4.w};
#pragma unroll
            for (int i = 0; i < 4; ++i)
#pragma unroll
                for (int j = 0; j < 4; ++j)
                    acc[i][j] = fmaf(av[i], bv[j], acc[i][j]);
        }
    }
    const float4 bb = *(const float4*)(bias + col0 + tc * 4);
#pragma unroll
    for (int i = 0; i < 4; ++i) {
        float4 o;
        o.x = acc[i][0] + bb.x; o.y = acc[i][1] + bb.y;
        o.z = acc[i][2] + bb.z; o.w = acc[i][3] + bb.w;
        *(float4*)(out + (size_t)(row0 + tr * 4 + i) * HID + col0 + tc * 4) = o;
    }
}

// y2 = relu(bn(y1)) @ W2 + b2   (BN+ReLU fused into A-load)
__global__ __launch_bounds__(256) void gemm2_kernel(
    const float* __restrict__ y1, const float* __restrict__ scale,
    const float* __restrict__ shift, const float* __restrict__ W,
    const float* __restrict__ bias, float* __restrict__ out)
{
    __shared__ __align__(16) float As[BKT][PADL];
    __shared__ __align__(16) float Bs[BKT][PADL];
    const int tid = threadIdx.x;
    const int row0 = blockIdx.y * BM;
    const int col0 = blockIdx.x * BN;
    const int tr = tid / 16, tc = tid % 16;
    const int ar = tid / 4, ak = (tid % 4) * 4;
    const int bk = tid / 16, bc = (tid % 16) * 4;
    float acc[4][4] = {};

    for (int kt = 0; kt < HID / BKT; ++kt) {
        const int k0 = kt * BKT;
        float4 a4 = *(const float4*)(y1 + (size_t)(row0 + ar) * HID + (k0 + ak));
        const float4 sc = *(const float4*)(scale + k0 + ak);
        const float4 sh = *(const float4*)(shift + k0 + ak);
        a4.x = fmaxf(fmaf(a4.x, sc.x, sh.x), 0.0f);
        a4.y = fmaxf(fmaf(a4.y, sc.y, sh.y), 0.0f);
        a4.z = fmaxf(fmaf(a4.z, sc.z, sh.z), 0.0f);
        a4.w = fmaxf(fmaf(a4.w, sc.w, sh.w), 0.0f);
        float4 b4 = *(const float4*)(W + (size_t)(k0 + bk) * HID + col0 + bc);
        __syncthreads();
        As[ak + 0][ar] = a4.x; As[ak + 1][ar] = a4.y;
        As[ak + 2][ar] = a4.z; As[ak + 3][ar] = a4.w;
        *(float4*)(&Bs[bk][bc]) = b4;
        __syncthreads();
#pragma unroll
        for (int k = 0; k < BKT; ++k) {
            const float4 av4 = *(const float4*)(&As[k][tr * 4]);
            const float4 bv4 = *(const float4*)(&Bs[k][tc * 4]);
            const float av[4] = {av4.x, av4.y, av4.z, av4.w};
            const float bv[4] = {bv4.x, bv4.y, bv4.z, bv4.w};
#pragma unroll
            for (int i = 0; i < 4; ++i)
#pragma unroll
                for (int j = 0; j < 4; ++j)
                    acc[i][j] = fmaf(av[i], bv[j], acc[i][j]);
        }
    }
    const float4 bb = *(const float4*)(bias + col0 + tc * 4);
#pragma unroll
    for (int i = 0; i < 4; ++i) {
        float4 o;
        o.x = acc[i][0] + bb.x; o.y = acc[i][1] + bb.y;
        o.z = acc[i][2] + bb.z; o.w = acc[i][3] + bb.w;
        *(float4*)(out + (size_t)(row0 + tr * 4 + i) * HID + col0 + tc * 4) = o;
    }
}

// ----------------------------------------------------- BN stats (2-stage)
__global__ __launch_bounds__(256) void bn_stats_kernel(
    const float* __restrict__ y, float* __restrict__ psum, float* __restrict__ psq)
{
    const int c = threadIdx.x;
    const size_t r0 = (size_t)blockIdx.x * 256;
    float s = 0.0f, q = 0.0f;
    for (int r = 0; r < 256; ++r) {
        float v = y[(r0 + r) * HID + c];
        s += v;
        q = fmaf(v, v, q);
    }
    psum[blockIdx.x * 256 + c] = s;
    psq[blockIdx.x * 256 + c] = q;
}

__global__ __launch_bounds__(256) void bn_finalize_kernel(
    const float* __restrict__ psum, const float* __restrict__ psq,
    const float* __restrict__ g, const float* __restrict__ be,
    float* __restrict__ scale, float* __restrict__ shift)
{
    const int c = threadIdx.x;
    float s = 0.0f, q = 0.0f;
    for (int b = 0; b < 256; ++b) { s += psum[b * 256 + c]; q += psq[b * 256 + c]; }
    const float inv_n = 1.0f / (float)N1T;
    const float mu = s * inv_n;
    const float var = fmaxf(q * inv_n - mu * mu, 0.0f);
    const float sc = g[c] * rsqrtf(var + BN_EPS);
    scale[c] = sc;
    shift[c] = be[c] - mu * sc;
}

// --------------------------------------------------------- final BN+ReLU
__global__ __launch_bounds__(256) void bn_apply_kernel(
    const float* __restrict__ y, const float* __restrict__ scale,
    const float* __restrict__ shift, float* __restrict__ out)
{
    const size_t i = (size_t)blockIdx.x * 256 + threadIdx.x;  // float4 index
    const int c4 = (int)(i & 63) * 4;
    float4 v = ((const float4*)y)[i];
    const float4 sc = *(const float4*)(scale + c4);
    const float4 sh = *(const float4*)(shift + c4);
    float4 o;
    o.x = fmaxf(fmaf(v.x, sc.x, sh.x), 0.0f);
    o.y = fmaxf(fmaf(v.y, sc.y, sh.y), 0.0f);
    o.z = fmaxf(fmaf(v.z, sc.z, sh.z), 0.0f);
    o.w = fmaxf(fmaf(v.w, sc.w, sh.w), 0.0f);
    ((float4*)out)[i] = o;
}

// -------------------------------------------------------------- launcher
extern "C" void kernel_launch(void* const* d_in, const int* in_sizes, int n_in,
                              void* d_out, int out_size, void* d_ws, size_t ws_size,
                              hipStream_t stream)
{
    const float* xyz1    = (const float*)d_in[0];
    const float* points1 = (const float*)d_in[1];
    const float* xyz2    = (const float*)d_in[2];
    const float* points2 = (const float*)d_in[3];
    // d_in[4], d_in[5]: offsets — uniform batching, unused
    const float* W1  = (const float*)d_in[6];
    const float* b1  = (const float*)d_in[7];
    const float* g1  = (const float*)d_in[8];
    const float* be1 = (const float*)d_in[9];
    const float* W2  = (const float*)d_in[10];
    const float* b2  = (const float*)d_in[11];
    const float* g2  = (const float*)d_in[12];
    const float* be2 = (const float*)d_in[13];
    float* out = (float*)d_out;

    char* ws = (char*)d_ws;
    // layout (bytes):
    //   [0, 134217728)        interp [N1,512] f32 ; reused as y2 after GEMM1
    //   [134217728, +67108864) y1 [N1,256] f32
    //   then idx, w, psum, psq, scale/shift pairs
    float* interp = (float*)ws;
    float* y1     = (float*)(ws + 134217728);
    size_t off    = 134217728 + 67108864;
    int*   idx    = (int*)(ws + off);   off += (size_t)N1T * 3 * 4;
    float* w      = (float*)(ws + off); off += (size_t)N1T * 3 * 4;
    float* psum   = (float*)(ws + off); off += 256 * 256 * 4;
    float* psq    = (float*)(ws + off); off += 256 * 256 * 4;
    float* scale1 = (float*)(ws + off); off += 256 * 4;
    float* shift1 = (float*)(ws + off); off += 256 * 4;
    float* scale2 = (float*)(ws + off); off += 256 * 4;
    float* shift2 = (float*)(ws + off); off += 256 * 4;
    float* y2 = interp;  // reuse: interp dead after gemm1

    knn_kernel<<<256, 256, 0, stream>>>(xyz1, xyz2, idx, w);
    interp_kernel<<<N1T, 128, 0, stream>>>(points2, idx, w, interp);
    gemm1_kernel<<<dim3(HID / BN, N1T / BM), 256, 0, stream>>>(
        points1, interp, W1, b1, y1);
    bn_stats_kernel<<<256, 256, 0, stream>>>(y1, psum, psq);
    bn_finalize_kernel<<<1, 256, 0, stream>>>(psum, psq, g1, be1, scale1, shift1);
    gemm2_kernel<<<dim3(HID / BN, N1T / BM), 256, 0, stream>>>(
        y1, scale1, shift1, W2, b2, y2);
    bn_stats_kernel<<<256, 256, 0, stream>>>(y2, psum, psq);
    bn_finalize_kernel<<<1, 256, 0, stream>>>(psum, psq, g2, be2, scale2, shift2);
    bn_apply_kernel<<<(N1T * HID / 4) / 256, 256, 0, stream>>>(y2, scale2, shift2, out);
}

// Round 10
// 420.570 us; speedup vs baseline: 1.8420x; 1.8420x over previous
//
#include <hip/hip_runtime.h>
#include <math.h>

#define N1T 65536
#define N2T 16384
#define BSZ 8
#define N1B 8192   // points per batch in xyz1
#define N2B 2048   // points per batch in xyz2
#define C1 256
#define C2 512
#define K1 768     // C1 + C2
#define HID 256
#define BN_EPS 1e-5f

typedef short bf16x8 __attribute__((ext_vector_type(8)));
typedef float f32x4 __attribute__((ext_vector_type(4)));

// Exact single-rounded f32 ops via ISA — immune to -ffast-math / contraction.
__device__ __forceinline__ float mul_rn(float a, float b) {
    float r; asm("v_mul_f32 %0, %1, %2" : "=v"(r) : "v"(a), "v"(b)); return r;
}
__device__ __forceinline__ float add_rn(float a, float b) {
    float r; asm("v_add_f32 %0, %1, %2" : "=v"(r) : "v"(a), "v"(b)); return r;
}
__device__ __forceinline__ float sub_rn(float a, float b) {
    float r; asm("v_sub_f32 %0, %1, %2" : "=v"(r) : "v"(a), "v"(b)); return r;
}
__device__ __forceinline__ float fma_rn(float a, float b, float c) {
    float r; asm("v_fma_f32 %0, %1, %2, %3" : "=v"(r) : "v"(a), "v"(b), "v"(c)); return r;
}
// f32 -> bf16 round-to-nearest-even
__device__ __forceinline__ short f2bf(float f) {
    unsigned u = __builtin_bit_cast(unsigned, f);
    u += 0x7fffu + ((u >> 16) & 1u);
    return (short)(u >> 16);
}

// ---------------------------------------------------------------- KNN-3
// FROZEN (r9 verified): d2 = (qq - 2*dot) + kk, nofma qq/kk, fma-asc dot.
// Matches ref=np bit-for-bit ordering. Do not change the arithmetic.
__global__ __launch_bounds__(256) void knn_kernel(
    const float* __restrict__ xyz1, const float* __restrict__ xyz2,
    int* __restrict__ idx_out, float* __restrict__ w_out)
{
    __shared__ float sx[N2B], sy[N2B], sz[N2B], skk[N2B];
    const int tid = threadIdx.x;
    const int qbase = blockIdx.x * 256;      // 256 blocks x 256 queries
    const int batch = qbase / N1B;           // block never straddles batches
    const float* k2 = xyz2 + (size_t)batch * N2B * 3;
    for (int i = tid; i < N2B * 3; i += 256) {
        float v = k2[i];
        int p = i / 3, c = i - 3 * p;
        if (c == 0) sx[p] = v; else if (c == 1) sy[p] = v; else sz[p] = v;
    }
    __syncthreads();
    for (int p = tid; p < N2B; p += 256) {
        float xx = mul_rn(sx[p], sx[p]);
        float yy = mul_rn(sy[p], sy[p]);
        float zz = mul_rn(sz[p], sz[p]);
        skk[p] = add_rn(add_rn(xx, yy), zz);
    }
    __syncthreads();

    const int q = qbase + tid;
    const float qx = xyz1[q * 3 + 0], qy = xyz1[q * 3 + 1], qz = xyz1[q * 3 + 2];
    const float qq = add_rn(add_rn(mul_rn(qx, qx), mul_rn(qy, qy)), mul_rn(qz, qz));
    float b0 = 1e30f, b1 = 1e30f, b2 = 1e30f;
    int i0 = 0, i1 = 0, i2 = 0;
#pragma unroll 4
    for (int j = 0; j < N2B; ++j) {
        float p0 = mul_rn(qx, sx[j]);
        float dt = fma_rn(qz, sz[j], fma_rn(qy, sy[j], p0));
        float d  = add_rn(sub_rn(qq, add_rn(dt, dt)), skk[j]);
        if (d < b2) {
            if (d < b1) {
                b2 = b1; i2 = i1;
                if (d < b0) { b1 = b0; i1 = i0; b0 = d; i0 = j; }
                else        { b1 = d;  i1 = j; }
            } else { b2 = d; i2 = j; }
        }
    }
    float d0s = __fsqrt_rn(fmaxf(b0, 0.0f));
    float d1s = __fsqrt_rn(fmaxf(b1, 0.0f));
    float d2s = __fsqrt_rn(fmaxf(b2, 0.0f));
    float r0 = __fdiv_rn(1.0f, add_rn(d0s, 1e-8f));
    float r1 = __fdiv_rn(1.0f, add_rn(d1s, 1e-8f));
    float r2 = __fdiv_rn(1.0f, add_rn(d2s, 1e-8f));
    float rs = add_rn(add_rn(r0, r1), r2);
    w_out[q * 3 + 0] = __fdiv_rn(r0, rs);
    w_out[q * 3 + 1] = __fdiv_rn(r1, rs);
    w_out[q * 3 + 2] = __fdiv_rn(r2, rs);
    idx_out[q * 3 + 0] = batch * N2B + i0;
    idx_out[q * 3 + 1] = batch * N2B + i1;
    idx_out[q * 3 + 2] = batch * N2B + i2;
}

// ------------------------------------------------- IDW interpolation gather
// f32 exact arithmetic, output cast to bf16 (GEMM A operand; halves traffic).
__global__ __launch_bounds__(128) void interp_kernel(
    const float* __restrict__ points2, const int* __restrict__ idx,
    const float* __restrict__ w, short* __restrict__ interpb)
{
    const int row = blockIdx.x;
    const int c4 = threadIdx.x;          // 4 cols per thread, 128*4 = 512
    const int j0 = idx[row * 3 + 0], j1 = idx[row * 3 + 1], j2 = idx[row * 3 + 2];
    const float w0 = w[row * 3 + 0], w1 = w[row * 3 + 1], w2 = w[row * 3 + 2];
    const float4 a = ((const float4*)(points2 + (size_t)j0 * C2))[c4];
    const float4 b = ((const float4*)(points2 + (size_t)j1 * C2))[c4];
    const float4 c = ((const float4*)(points2 + (size_t)j2 * C2))[c4];
    float ox = add_rn(add_rn(mul_rn(a.x, w0), mul_rn(b.x, w1)), mul_rn(c.x, w2));
    float oy = add_rn(add_rn(mul_rn(a.y, w0), mul_rn(b.y, w1)), mul_rn(c.y, w2));
    float oz = add_rn(add_rn(mul_rn(a.z, w0), mul_rn(b.z, w1)), mul_rn(c.z, w2));
    float ow = add_rn(add_rn(mul_rn(a.w, w0), mul_rn(b.w, w1)), mul_rn(c.w, w2));
    short4 o4; o4.x = f2bf(ox); o4.y = f2bf(oy); o4.z = f2bf(oz); o4.w = f2bf(ow);
    *(short4*)(interpb + (size_t)row * C2 + c4 * 4) = o4;
}

// ------------------------------------------------------ prep: casts/transposes
__global__ __launch_bounds__(256) void cast_p1_kernel(
    const float* __restrict__ p1, short* __restrict__ p1b)
{
    const size_t i = ((size_t)blockIdx.x * 256 + threadIdx.x) * 8;
    float4 u0 = *(const float4*)(p1 + i);
    float4 u1 = *(const float4*)(p1 + i + 4);
    bf16x8 v;
    v[0] = f2bf(u0.x); v[1] = f2bf(u0.y); v[2] = f2bf(u0.z); v[3] = f2bf(u0.w);
    v[4] = f2bf(u1.x); v[5] = f2bf(u1.y); v[6] = f2bf(u1.z); v[7] = f2bf(u1.w);
    *(bf16x8*)(p1b + i) = v;
}

// W[K][N] f32 -> WT[N][K] bf16
__global__ __launch_bounds__(256) void transpose_w_kernel(
    const float* __restrict__ Win, short* __restrict__ WT, int K, int N)
{
    const int e = blockIdx.x * 256 + threadIdx.x;
    const int k = e / N, n = e % N;
    WT[(size_t)n * K + k] = f2bf(Win[e]);
}

// --------------------------------------------- bf16 MFMA GEMMs (128x128 tile)
// 4 waves (2x2), each wave 64x64 = 4x4 frags of 16x16x32.
// LDS [128][40] bf16 (pad 8 -> 80B stride: frag-read conflicts 2-way = free).
#define LDP 40

// y1 = concat(points1, interp) @ W1 + b1   (A bf16, B = W1^T bf16, acc f32)
__global__ __launch_bounds__(256) void gemm1m_kernel(
    const short* __restrict__ p1b, const short* __restrict__ interpb,
    const short* __restrict__ w1t, const float* __restrict__ bias,
    float* __restrict__ y1)
{
    __shared__ short As[128][LDP];
    __shared__ short Bs[128][LDP];
    const int tid = threadIdx.x;
    const int lane = tid & 63, wv = tid >> 6;
    const int wr = wv >> 1, wc = wv & 1;
    const int l16 = lane & 15, kh = (lane >> 4) * 8;
    const int row0 = blockIdx.y * 128, col0 = blockIdx.x * 128;
    f32x4 acc[4][4];
#pragma unroll
    for (int m = 0; m < 4; ++m)
#pragma unroll
        for (int n = 0; n < 4; ++n) acc[m][n] = (f32x4){0.f, 0.f, 0.f, 0.f};

    const int c0 = tid * 2;                 // 2 chunks of 8 bf16 per thread
    const int r0c = c0 >> 2, kc0 = (c0 & 3) * 8;
    const int r1c = (c0 + 1) >> 2, kc1 = ((c0 + 1) & 3) * 8;

    for (int kt = 0; kt < K1 / 32; ++kt) {
        const int k0 = kt * 32;
        bf16x8 va, vb, wa, wb;
        if (k0 < C1) {
            va = *(const bf16x8*)(p1b + (size_t)(row0 + r0c) * C1 + k0 + kc0);
            vb = *(const bf16x8*)(p1b + (size_t)(row0 + r1c) * C1 + k0 + kc1);
        } else {
            va = *(const bf16x8*)(interpb + (size_t)(row0 + r0c) * C2 + (k0 - C1) + kc0);
            vb = *(const bf16x8*)(interpb + (size_t)(row0 + r1c) * C2 + (k0 - C1) + kc1);
        }
        wa = *(const bf16x8*)(w1t + (size_t)(col0 + r0c) * K1 + k0 + kc0);
        wb = *(const bf16x8*)(w1t + (size_t)(col0 + r1c) * K1 + k0 + kc1);
        __syncthreads();
        *(bf16x8*)(&As[r0c][kc0]) = va;
        *(bf16x8*)(&As[r1c][kc1]) = vb;
        *(bf16x8*)(&Bs[r0c][kc0]) = wa;
        *(bf16x8*)(&Bs[r1c][kc1]) = wb;
        __syncthreads();

        bf16x8 af[4], bf[4];
#pragma unroll
        for (int m = 0; m < 4; ++m)
            af[m] = *(const bf16x8*)(&As[wr * 64 + m * 16 + l16][kh]);
#pragma unroll
        for (int n = 0; n < 4; ++n)
            bf[n] = *(const bf16x8*)(&Bs[wc * 64 + n * 16 + l16][kh]);
#pragma unroll
        for (int m = 0; m < 4; ++m)
#pragma unroll
            for (int n = 0; n < 4; ++n)
                acc[m][n] = __builtin_amdgcn_mfma_f32_16x16x32_bf16(
                    af[m], bf[n], acc[m][n], 0, 0, 0);
    }
    // C/D layout: col = lane&15, row = (lane>>4)*4 + j   [guide m89]
#pragma unroll
    for (int n = 0; n < 4; ++n) {
        const int col = col0 + wc * 64 + n * 16 + l16;
        const float bv = bias[col];
#pragma unroll
        for (int m = 0; m < 4; ++m) {
            const int rowb = row0 + wr * 64 + m * 16 + (lane >> 4) * 4;
#pragma unroll
            for (int j = 0; j < 4; ++j)
                y1[(size_t)(rowb + j) * HID + col] = acc[m][n][j] + bv;
        }
    }
}

// y2 = relu(bn(y1)) @ W2 + b2   (BN+ReLU+bf16-cast fused into A staging)
__global__ __launch_bounds__(256) void gemm2m_kernel(
    const float* __restrict__ y1, const float* __restrict__ scale,
    const float* __restrict__ shift, const short* __restrict__ w2t,
    const float* __restrict__ bias, float* __restrict__ y2)
{
    __shared__ short As[128][LDP];
    __shared__ short Bs[128][LDP];
    const int tid = threadIdx.x;
    const int lane = tid & 63, wv = tid >> 6;
    const int wr = wv >> 1, wc = wv & 1;
    const int l16 = lane & 15, kh = (lane >> 4) * 8;
    const int row0 = blockIdx.y * 128, col0 = blockIdx.x * 128;
    f32x4 acc[4][4];
#pragma unroll
    for (int m = 0; m < 4; ++m)
#pragma unroll
        for (int n = 0; n < 4; ++n) acc[m][n] = (f32x4){0.f, 0.f, 0.f, 0.f};

    const int c0 = tid * 2;
    const int r0c = c0 >> 2, kc0 = (c0 & 3) * 8;
    const int r1c = (c0 + 1) >> 2, kc1 = ((c0 + 1) & 3) * 8;

    for (int kt = 0; kt < HID / 32; ++kt) {
        const int k0 = kt * 32;
        // chunk 0: 8 floats -> bn-relu -> 8 bf16
        float4 u0 = *(const float4*)(y1 + (size_t)(row0 + r0c) * HID + k0 + kc0);
        float4 u1 = *(const float4*)(y1 + (size_t)(row0 + r0c) * HID + k0 + kc0 + 4);
        float4 s0 = *(const float4*)(scale + k0 + kc0);
        float4 s1 = *(const float4*)(scale + k0 + kc0 + 4);
        float4 h0 = *(const float4*)(shift + k0 + kc0);
        float4 h1 = *(const float4*)(shift + k0 + kc0 + 4);
        bf16x8 va;
        va[0] = f2bf(fmaxf(fmaf(u0.x, s0.x, h0.x), 0.f));
        va[1] = f2bf(fmaxf(fmaf(u0.y, s0.y, h0.y), 0.f));
        va[2] = f2bf(fmaxf(fmaf(u0.z, s0.z, h0.z), 0.f));
        va[3] = f2bf(fmaxf(fmaf(u0.w, s0.w, h0.w), 0.f));
        va[4] = f2bf(fmaxf(fmaf(u1.x, s1.x, h1.x), 0.f));
        va[5] = f2bf(fmaxf(fmaf(u1.y, s1.y, h1.y), 0.f));
        va[6] = f2bf(fmaxf(fmaf(u1.z, s1.z, h1.z), 0.f));
        va[7] = f2bf(fmaxf(fmaf(u1.w, s1.w, h1.w), 0.f));
        // chunk 1
        float4 u2 = *(const float4*)(y1 + (size_t)(row0 + r1c) * HID + k0 + kc1);
        float4 u3 = *(const float4*)(y1 + (size_t)(row0 + r1c) * HID + k0 + kc1 + 4);
        float4 s2 = *(const float4*)(scale + k0 + kc1);
        float4 s3 = *(const float4*)(scale + k0 + kc1 + 4);
        float4 h2 = *(const float4*)(shift + k0 + kc1);
        float4 h3 = *(const float4*)(shift + k0 + kc1 + 4);
        bf16x8 vb;
        vb[0] = f2bf(fmaxf(fmaf(u2.x, s2.x, h2.x), 0.f));
        vb[1] = f2bf(fmaxf(fmaf(u2.y, s2.y, h2.y), 0.f));
        vb[2] = f2bf(fmaxf(fmaf(u2.z, s2.z, h2.z), 0.f));
        vb[3] = f2bf(fmaxf(fmaf(u2.w, s2.w, h2.w), 0.f));
        vb[4] = f2bf(fmaxf(fmaf(u3.x, s3.x, h3.x), 0.f));
        vb[5] = f2bf(fmaxf(fmaf(u3.y, s3.y, h3.y), 0.f));
        vb[6] = f2bf(fmaxf(fmaf(u3.z, s3.z, h3.z), 0.f));
        vb[7] = f2bf(fmaxf(fmaf(u3.w, s3.w, h3.w), 0.f));
        bf16x8 wa = *(const bf16x8*)(w2t + (size_t)(col0 + r0c) * HID + k0 + kc0);
        bf16x8 wb = *(const bf16x8*)(w2t + (size_t)(col0 + r1c) * HID + k0 + kc1);
        __syncthreads();
        *(bf16x8*)(&As[r0c][kc0]) = va;
        *(bf16x8*)(&As[r1c][kc1]) = vb;
        *(bf16x8*)(&Bs[r0c][kc0]) = wa;
        *(bf16x8*)(&Bs[r1c][kc1]) = wb;
        __syncthreads();

        bf16x8 af[4], bf[4];
#pragma unroll
        for (int m = 0; m < 4; ++m)
            af[m] = *(const bf16x8*)(&As[wr * 64 + m * 16 + l16][kh]);
#pragma unroll
        for (int n = 0; n < 4; ++n)
            bf[n] = *(const bf16x8*)(&Bs[wc * 64 + n * 16 + l16][kh]);
#pragma unroll
        for (int m = 0; m < 4; ++m)
#pragma unroll
            for (int n = 0; n < 4; ++n)
                acc[m][n] = __builtin_amdgcn_mfma_f32_16x16x32_bf16(
                    af[m], bf[n], acc[m][n], 0, 0, 0);
    }
#pragma unroll
    for (int n = 0; n < 4; ++n) {
        const int col = col0 + wc * 64 + n * 16 + l16;
        const float bv = bias[col];
#pragma unroll
        for (int m = 0; m < 4; ++m) {
            const int rowb = row0 + wr * 64 + m * 16 + (lane >> 4) * 4;
#pragma unroll
            for (int j = 0; j < 4; ++j)
                y2[(size_t)(rowb + j) * HID + col] = acc[m][n][j] + bv;
        }
    }
}

// ----------------------------------------------------- BN stats (2-stage)
__global__ __launch_bounds__(256) void bn_stats_kernel(
    const float* __restrict__ y, float* __restrict__ psum, float* __restrict__ psq)
{
    const int c = threadIdx.x;
    const size_t r0 = (size_t)blockIdx.x * 256;
    float s = 0.0f, q = 0.0f;
    for (int r = 0; r < 256; ++r) {
        float v = y[(r0 + r) * HID + c];
        s += v;
        q = fmaf(v, v, q);
    }
    psum[blockIdx.x * 256 + c] = s;
    psq[blockIdx.x * 256 + c] = q;
}

__global__ __launch_bounds__(256) void bn_finalize_kernel(
    const float* __restrict__ psum, const float* __restrict__ psq,
    const float* __restrict__ g, const float* __restrict__ be,
    float* __restrict__ scale, float* __restrict__ shift)
{
    const int c = threadIdx.x;
    float s = 0.0f, q = 0.0f;
    for (int b = 0; b < 256; ++b) { s += psum[b * 256 + c]; q += psq[b * 256 + c]; }
    const float inv_n = 1.0f / (float)N1T;
    const float mu = s * inv_n;
    const float var = fmaxf(q * inv_n - mu * mu, 0.0f);
    const float sc = g[c] * rsqrtf(var + BN_EPS);
    scale[c] = sc;
    shift[c] = be[c] - mu * sc;
}

// --------------------------------------------------------- final BN+ReLU
__global__ __launch_bounds__(256) void bn_apply_kernel(
    const float* __restrict__ y, const float* __restrict__ scale,
    const float* __restrict__ shift, float* __restrict__ out)
{
    const size_t i = (size_t)blockIdx.x * 256 + threadIdx.x;  // float4 index
    const int c4 = (int)(i & 63) * 4;
    float4 v = ((const float4*)y)[i];
    const float4 sc = *(const float4*)(scale + c4);
    const float4 sh = *(const float4*)(shift + c4);
    float4 o;
    o.x = fmaxf(fmaf(v.x, sc.x, sh.x), 0.0f);
    o.y = fmaxf(fmaf(v.y, sc.y, sh.y), 0.0f);
    o.z = fmaxf(fmaf(v.z, sc.z, sh.z), 0.0f);
    o.w = fmaxf(fmaf(v.w, sc.w, sh.w), 0.0f);
    ((float4*)out)[i] = o;
}

// -------------------------------------------------------------- launcher
extern "C" void kernel_launch(void* const* d_in, const int* in_sizes, int n_in,
                              void* d_out, int out_size, void* d_ws, size_t ws_size,
                              hipStream_t stream)
{
    const float* xyz1    = (const float*)d_in[0];
    const float* points1 = (const float*)d_in[1];
    const float* xyz2    = (const float*)d_in[2];
    const float* points2 = (const float*)d_in[3];
    const float* W1  = (const float*)d_in[6];
    const float* b1  = (const float*)d_in[7];
    const float* g1  = (const float*)d_in[8];
    const float* be1 = (const float*)d_in[9];
    const float* W2  = (const float*)d_in[10];
    const float* b2  = (const float*)d_in[11];
    const float* g2  = (const float*)d_in[12];
    const float* be2 = (const float*)d_in[13];
    float* out = (float*)d_out;

    char* ws = (char*)d_ws;
    // layout (bytes):
    //   [0, 67108864)   interp bf16 [N1,512]; reused as y2 f32 [N1,256] after gemm1
    //   [67108864, +67108864)  y1 f32 [N1,256]
    //   [134217728, +33554432) points1 bf16
    //   then W1T/W2T bf16, idx, w, psum, psq, scale/shift
    short* interpb = (short*)ws;
    float* y1      = (float*)(ws + 67108864);
    short* p1b     = (short*)(ws + 134217728);
    size_t off     = 134217728 + 33554432;
    short* w1t     = (short*)(ws + off); off += (size_t)K1 * HID * 2;
    short* w2t     = (short*)(ws + off); off += (size_t)HID * HID * 2;
    int*   idx     = (int*)(ws + off);   off += (size_t)N1T * 3 * 4;
    float* w       = (float*)(ws + off); off += (size_t)N1T * 3 * 4;
    float* psum    = (float*)(ws + off); off += 256 * 256 * 4;
    float* psq     = (float*)(ws + off); off += 256 * 256 * 4;
    float* scale1  = (float*)(ws + off); off += 256 * 4;
    float* shift1  = (float*)(ws + off); off += 256 * 4;
    float* scale2  = (float*)(ws + off); off += 256 * 4;
    float* shift2  = (float*)(ws + off); off += 256 * 4;
    float* y2 = (float*)interpb;  // reuse: interp dead after gemm1

    cast_p1_kernel<<<N1T * C1 / 8 / 256, 256, 0, stream>>>(points1, p1b);
    transpose_w_kernel<<<K1 * HID / 256, 256, 0, stream>>>(W1, w1t, K1, HID);
    transpose_w_kernel<<<HID * HID / 256, 256, 0, stream>>>(W2, w2t, HID, HID);
    knn_kernel<<<256, 256, 0, stream>>>(xyz1, xyz2, idx, w);
    interp_kernel<<<N1T, 128, 0, stream>>>(points2, idx, w, interpb);
    gemm1m_kernel<<<dim3(HID / 128, N1T / 128), 256, 0, stream>>>(
        p1b, interpb, w1t, b1, y1);
    bn_stats_kernel<<<256, 256, 0, stream>>>(y1, psum, psq);
    bn_finalize_kernel<<<1, 256, 0, stream>>>(psum, psq, g1, be1, scale1, shift1);
    gemm2m_kernel<<<dim3(HID / 128, N1T / 128), 256, 0, stream>>>(
        y1, scale1, shift1, w2t, b2, y2);
    bn_stats_kernel<<<256, 256, 0, stream>>>(y2, psum, psq);
    bn_finalize_kernel<<<1, 256, 0, stream>>>(psum, psq, g2, be2, scale2, shift2);
    bn_apply_kernel<<<(N1T * HID / 4) / 256, 256, 0, stream>>>(y2, scale2, shift2, out);
}